// Round 10
// baseline (835.367 us; speedup 1.0000x reference)
//
#include <hip/hip_runtime.h>
#include <math.h>

// clDice topology loss, round 14: R13's rebalance, spill-proofed.
// R13 failed on register budget, not on the theory: (320,5) capped the
// allocator at ~51 (pool-256 model) while two inlined dilate_phase bodies
// pushed natural use past it -> 230 MB spill, 35% occupancy. Fixes:
// (a) __launch_bounds__(320) with NO min-waves arg (R10: no-arg = natural
//     allocation), (b) single dilate_phase call site: epilogue folded into
//     the loop with uniform-branch barriers (if it<10).
// Layout (unchanged from R13): 3 erode waves (48 segs x 2 rows x 4 chunks)
// + 2 dilate waves; erode ~130 inst/phase ~= dilate ~140 -> balanced poles
// vs R11's erode-pole 195. Freshness proof for 2-row segs verified by
// R13's absmax 0.0. In-place single buffer as R7-R13.

typedef unsigned int u32;
typedef _Float16 h2 __attribute__((ext_vector_type(2)));

#define STRD 52
#define BB   0x7BFF7BFFu   // +65504 x2 (erode pad)
#define NB   0xFBFFFBFFu   // -65504 x2 (dilate edge substitute)

__device__ __forceinline__ u32 ab(u32 hi, u32 lo) {
  return __builtin_amdgcn_alignbit(hi, lo, 16);
}
__device__ __forceinline__ u32 bcu(h2 x) { return __builtin_bit_cast(u32, x); }
__device__ __forceinline__ h2  bch(u32 x) { return __builtin_bit_cast(h2, x); }
__device__ __forceinline__ u32 pmin(u32 a, u32 b) {
  return bcu(__builtin_elementwise_min(bch(a), bch(b)));
}
__device__ __forceinline__ u32 pmax(u32 a, u32 b) {
  return bcu(__builtin_elementwise_max(bch(a), bch(b)));
}
__device__ __forceinline__ u32 pmin3(u32 a, u32 b, u32 c) { return pmin(pmin(a, b), c); }
__device__ __forceinline__ u32 pmax3(u32 a, u32 b, u32 c) { return pmax(pmax(a, b), c); }
// skel >= 0 always, so max(skel, relu(d)) == max(skel, d).
__device__ __forceinline__ u32 skup(u32 sk, u32 im, u32 op) {
  h2 d = bch(im) - bch(op);
  return bcu(__builtin_elementwise_max(bch(sk), d));
}
__device__ __forceinline__ float sigmoidf_(float x) {
  return 1.0f / (1.0f + __expf(-x));
}

__device__ __forceinline__ void load12(const u32* __restrict__ p,
                                       u32* __restrict__ r) {
  uint4 a = *(const uint4*)p;
  uint4 b = *(const uint4*)(p + 4);
  uint4 c = *(const uint4*)(p + 8);
  r[0]=a.x; r[1]=a.y; r[2]=a.z; r[3]=a.w;
  r[4]=b.x; r[5]=b.y; r[6]=b.z; r[7]=b.w;
  r[8]=c.x; r[9]=c.y; r[10]=c.z; r[11]=c.w;
}

__device__ __forceinline__ void store12(u32* __restrict__ q,
                                        const u32* __restrict__ r) {
  *(uint4*)(q)     = make_uint4(r[0], r[1], r[2],  r[3]);
  *(uint4*)(q + 4) = make_uint4(r[4], r[5], r[6],  r[7]);
  *(uint4*)(q + 8) = make_uint4(r[8], r[9], r[10], r[11]);
}

// Horizontal 3-wide min over a 12-dw vmin row; halos pre-fetched.
__device__ __forceinline__ void hrow12(const u32* __restrict__ v,
                                       u32 hl, u32 hr,
                                       u32* __restrict__ o) {
  u32 m0 = ab(v[0], hl);
  #pragma unroll
  for (int i = 0; i < 12; ++i) {
    u32 m1 = (i < 11) ? ab(v[i + 1], v[i]) : ab(hr, v[11]);
    o[i] = pmin3(m0, v[i], m1);
    m0 = m1;
  }
}

// Erode compute, 2-row seg: reads halo rows as2-1, as2+2 of E^ph from E
// (center rows as2, as2+1 carried in e0, e1), leaves E^(ph+1) rows
// as2..as2+1 in e0, e1. NO stores (caller stores after mid-phase barrier).
// FIRST: also load center rows (ph0, no carry yet).
template <bool FIRST>
__device__ __forceinline__ void erode_compute(
    const u32* __restrict__ E,
    int as2, int eoff, int pu, int pd, bool c0, bool c3,
    u32* __restrict__ e0, u32* __restrict__ e1)
{
  const u32* pr = E + (as2 - 1) * STRD + eoff;
  u32 rT[12], rB[12];
  load12(pr, rT);
  if (FIRST) {
    load12(pr + STRD,     e0);
    load12(pr + 2 * STRD, e1);
  }
  load12(pr + 3 * STRD, rB);
  u32 tt[12], v0[12], v1[12];
  #pragma unroll
  for (int i = 0; i < 12; ++i) tt[i] = pmin(e0[i], e1[i]);
  #pragma unroll
  for (int i = 0; i < 12; ++i) v0[i] = pmin(rT[i], tt[i]);
  #pragma unroll
  for (int i = 0; i < 12; ++i) v1[i] = pmin(tt[i], rB[i]);
  // halos for both rows issued up-front (hide bpermute latency)
  u32 hl0 = (u32)__builtin_amdgcn_ds_bpermute(pu, (int)v0[11]);
  u32 hr0 = (u32)__builtin_amdgcn_ds_bpermute(pd, (int)v0[0]);
  u32 hl1 = (u32)__builtin_amdgcn_ds_bpermute(pu, (int)v1[11]);
  u32 hr1 = (u32)__builtin_amdgcn_ds_bpermute(pd, (int)v1[0]);
  hl0 = c0 ? BB : hl0;  hr0 = c3 ? BB : hr0;
  hl1 = c0 ? BB : hl1;  hr1 = c3 ? BB : hr1;
  hrow12(v0, hl0, hr0, e0);
  hrow12(v1, hl1, hr1, e1);
}

__device__ __forceinline__ void erode_store(
    u32* __restrict__ E, int as2, int eoff,
    const u32* __restrict__ e0, const u32* __restrict__ e1)
{
  u32* qw = E + as2 * STRD + eoff;
  store12(qw,        e0);
  store12(qw + STRD, e1);
}

// One dilate iteration for one lane (R11 body: all-b128, img via center
// reload): vertical-first 3x3 max over E rows dr-1..dr+1 (out-of-image rows
// redirected to the -BIG LDS row), horizontal pass, skup against img
// (E^{it-1} center, in regs), img <- reloaded E^{it} center. Pure reads.
__device__ __forceinline__ void dilate_phase(
    const u32* __restrict__ E, const u32* __restrict__ NBR,
    int dr, int db, bool bu, bool bd, bool lfix, bool rfix,
    u32* __restrict__ img, u32* __restrict__ sk)
{
  const u32* pm = bu ? (E + (dr - 1) * STRD + db) : (NBR + db);
  const u32* pc = E + dr * STRD + db;
  const u32* pp = bd ? (E + (dr + 1) * STRD + db) : (NBR + db);
  u32 vm[21];      // indices 3..20 used
  #pragma unroll
  for (int j = 0; j < 6; ++j) {
    uint4 x = *(const uint4*)(pm + 4 * j);
    uint4 y = *(const uint4*)(pc + 4 * j);
    uint4 z = *(const uint4*)(pp + 4 * j);
    u32 xs[4] = {x.x, x.y, x.z, x.w};
    u32 ys[4] = {y.x, y.y, y.z, y.w};
    u32 zs[4] = {z.x, z.y, z.z, z.w};
    #pragma unroll
    for (int k = 0; k < 4; ++k) {
      int i = 4 * j + k;
      if (i >= 3 && i <= 20) vm[i] = pmax3(xs[k], ys[k], zs[k]);
    }
  }
  if (lfix) vm[3]  = (vm[3]  & 0x0000FFFFu) | 0xFBFF0000u;  // col 15 -> -BIG
  if (rfix) vm[20] = (vm[20] & 0xFFFF0000u) | 0x0000FBFFu;  // col 80 -> -BIG
  u32 m0 = ab(vm[4], vm[3]);
  #pragma unroll
  for (int j = 0; j < 4; ++j) {
    const uint4 y = *(const uint4*)(pc + 4 + 4 * j);  // center-row reload
    const u32 yk[4] = {y.x, y.y, y.z, y.w};
    #pragma unroll
    for (int k = 0; k < 4; ++k) {
      const int i = 4 * j + k;
      u32 m1 = ab(vm[i + 5], vm[i + 4]);
      u32 op = pmax3(m0, vm[i + 4], m1);
      m0 = m1;
      sk[i] = skup(sk[i], img[i], op);
      img[i] = yk[k];
    }
  }
}

__global__ __launch_bounds__(320) void skel_tile_kernel(
    const float* __restrict__ pred, const float* __restrict__ gt,
    float* __restrict__ sums)
{
  // Single in-place buffer: rows 0..95 data (row r at r*STRD), row 96 = -BIG.
  __shared__ __align__(16) u32 L[STRD * 97];
  u32* const E = L;
  const u32* const NBR = L + STRD * 96;

  const int tile = blockIdx.x;   // 16x16 tiles of 64x64
  const int b    = blockIdx.y;   // batch 0..31
  const int s    = blockIdx.z;   // 0: skel(sigmoid(pred)), 1: skel(gt)
  const int txI = tile & 15, tyI = tile >> 4;
  const int x0 = txI * 64 - 16, y0 = tyI * 64 - 16;
  const int t  = threadIdx.x;
  const size_t base = (size_t)b << 20;
  const float* __restrict__ src  = s ? gt   : pred;
  const float* __restrict__ osrc = s ? pred : gt;

  // ---- -BIG row init (the only scratch row read) ----
  for (int i = t; i < STRD; i += 320) L[STRD * 96 + i] = NB;

  // ---- load rows 5..90 x 12 chunks of 8 halfs; out-of-image = +BIG ----
  for (int i = t; i < 86 * 12; i += 320) {
    int ci = i % 12, row = i / 12 + 5;
    int gy = y0 + row, gx0 = x0 + ci * 8;
    uint4 hv;
    if ((unsigned)gy < 1024u && gx0 >= 0 && gx0 + 8 <= 1024) {
      const size_t g = base + (size_t)gy * 1024 + gx0;
      const float4 f0 = *(const float4*)&src[g];
      const float4 f1 = *(const float4*)&src[g + 4];
      float ff[8] = {f0.x, f0.y, f0.z, f0.w, f1.x, f1.y, f1.z, f1.w};
      u32 d[4];
      #pragma unroll
      for (int e = 0; e < 4; ++e) {
        float a = ff[2 * e], bb2 = ff[2 * e + 1];
        if (s == 0) { a = sigmoidf_(a); bb2 = sigmoidf_(bb2); }
        h2 p; p[0] = (_Float16)a; p[1] = (_Float16)bb2;
        d[e] = bcu(p);
      }
      hv = make_uint4(d[0], d[1], d[2], d[3]);
    } else {
      u32 d[4];
      #pragma unroll
      for (int e = 0; e < 4; ++e) {
        float va = 65504.0f, vb = 65504.0f;
        int gxa = gx0 + 2 * e, gxb = gxa + 1;
        if ((unsigned)gy < 1024u && (unsigned)gxa < 1024u) {
          va = src[base + (size_t)gy * 1024 + gxa];
          if (s == 0) va = sigmoidf_(va);
        }
        if ((unsigned)gy < 1024u && (unsigned)gxb < 1024u) {
          vb = src[base + (size_t)gy * 1024 + gxb];
          if (s == 0) vb = sigmoidf_(vb);
        }
        h2 p; p[0] = (_Float16)va; p[1] = (_Float16)vb;
        d[e] = bcu(p);
      }
      hv = make_uint4(d[0], d[1], d[2], d[3]);
    }
    *(uint4*)&E[row * STRD + ci * 4] = hv;
  }
  __syncthreads();

  const int lane = t & 63, wid = t >> 6;

  // erode role (waves 0-2): seg = t>>2 (0..47, 2 rows each), chunk ec = t&3
  const int seg = t >> 2, ec = t & 3;
  const int as2 = 2 * seg;
  const bool c0 = (ec == 0), c3 = (ec == 3);
  const int pu = ((lane - 1) & 63) * 4;
  const int pd = ((lane + 1) & 63) * 4;
  const int eoff = 12 * ec;

  // dilate role (waves 3-4): q = wid-3, row dr = 16+lane
  const int q  = wid - 3;
  const int dr = 16 + lane;
  const int db = 4 + 16 * q;          // first dword of 24-dw read span
  const int gyD = y0 + dr;
  const bool bu = (gyD >= 1), bd = (gyD <= 1022);
  const bool lfix = (q == 0) && (txI == 0);
  const bool rfix = (q == 1) && (txI == 15);

  // Role-union register file: erode e0,e1 = st[0..23];
  // dilate img = st[0..15], skel = st[16..31].
  u32 st[32];
  u32* const e0 = st;
  u32* const e1 = st + 12;
  u32* const img = st;
  u32* const sk  = st + 16;

  // ---- phase 0 ----
  const bool a0 = !(as2 + 1 < 6 || as2 > 89);
  if (wid < 3) {
    if (a0) erode_compute<true>(E, as2, eoff, pu, pd, c0, c3, e0, e1);
  } else {
    #pragma unroll
    for (int i = 0; i < 16; ++i) sk[i] = 0;
    const u32* p = E + dr * STRD + db;
    #pragma unroll
    for (int i = 0; i < 4; ++i) {
      uint4 v = *(const uint4*)(p + 4 + 4 * i);
      img[4*i] = v.x; img[4*i+1] = v.y; img[4*i+2] = v.z; img[4*i+3] = v.w;
    }
  }
  __syncthreads();
  if (wid < 3 && a0) erode_store(E, as2, eoff, e0, e1);
  __syncthreads();

  // ---- phases 1..10 (single dilate call site; it==10 = barrier-free tail:
  //      erode inactive there, and reduction's red[] area (rows 0-1) is
  //      disjoint from dilate's reads (rows >= 15)) ----
  #pragma unroll 1
  for (int it = 1; it <= 10; ++it) {
    const bool act = (it < 10) && !(as2 + 1 < 6 + it || as2 > 89 - it);
    if (wid < 3) {
      if (act) erode_compute<false>(E, as2, eoff, pu, pd, c0, c3, e0, e1);
    } else {
      dilate_phase(E, NBR, dr, db, bu, bd, lfix, rfix, img, sk);
    }
    if (it < 10) {
      __syncthreads();
      if (wid < 3 && act) erode_store(E, as2, eoff, e0, e1);
      __syncthreads();
    }
  }

  // ---- fused reduction: s0 = sum(skel*other), s1 = sum(skel) ----
  float s0 = 0.f, s1 = 0.f;
  if (wid >= 3) {
    const int gxb = x0 + 2 * db + 8;  // global col of first skel half
    const size_t g = base + (size_t)gyD * 1024 + gxb;
    #pragma unroll
    for (int v4i = 0; v4i < 8; ++v4i) {
      const float4 f = *(const float4*)&osrc[g + 4 * v4i];
      float o0 = f.x, o1 = f.y, o2 = f.z, o3 = f.w;
      if (s == 1) {
        o0 = sigmoidf_(o0); o1 = sigmoidf_(o1);
        o2 = sigmoidf_(o2); o3 = sigmoidf_(o3);
      }
      h2 qa = bch(sk[2 * v4i]);
      h2 qb = bch(sk[2 * v4i + 1]);
      float a0 = (float)qa[0], a1 = (float)qa[1];
      float a2 = (float)qb[0], a3 = (float)qb[1];
      s0 += a0 * o0 + a1 * o1 + a2 * o2 + a3 * o3;
      s1 += a0 + a1 + a2 + a3;
    }
  }
  for (int off = 32; off >= 1; off >>= 1) {
    s0 += __shfl_down(s0, off, 64);
    s1 += __shfl_down(s1, off, 64);
  }
  // red area (L rows 0-1) is disjoint from dilate's reads (rows >= 15);
  // the barrier orders red[] writes before the t==0 read.
  float* red = (float*)L;
  if (lane == 0) { red[wid * 2] = s0; red[wid * 2 + 1] = s1; }
  __syncthreads();
  if (t == 0) {
    atomicAdd(&sums[(s * 32 + b) * 2 + 0], red[6] + red[8]);
    atomicAdd(&sums[(s * 32 + b) * 2 + 1], red[7] + red[9]);
  }
}

__global__ void finalize_kernel(const float* __restrict__ sums,
                                float* __restrict__ out)
{
  const int t = threadIdx.x;  // 64 threads
  float cl = 0.f;
  if (t < 32) {
    float pn = sums[t * 2 + 0],        pd = sums[t * 2 + 1];
    float sn = sums[(32 + t) * 2 + 0], sd = sums[(32 + t) * 2 + 1];
    float tprec = pn / (pd + 1e-6f);
    float tsens = sn / (sd + 1e-6f);
    cl = 2.f * tprec * tsens / (tprec + tsens + 1e-6f);
  }
  for (int off = 32; off >= 1; off >>= 1) cl += __shfl_down(cl, off, 64);
  if (t == 0) out[0] = 1.f - cl / 32.f;
}

extern "C" void kernel_launch(void* const* d_in, const int* in_sizes, int n_in,
                              void* d_out, int out_size, void* d_ws, size_t ws_size,
                              hipStream_t stream) {
  const float* pred = (const float*)d_in[0];
  const float* gt   = (const float*)d_in[1];
  float* sums = (float*)d_ws;  // 128 floats: [tensor][batch][{prod,sum}]
  hipMemsetAsync(sums, 0, 128 * sizeof(float), stream);
  dim3 grid(256, 32, 2);
  skel_tile_kernel<<<grid, dim3(320), 0, stream>>>(pred, gt, sums);
  finalize_kernel<<<1, 64, 0, stream>>>(sums, (float*)d_out);
}

// Round 11
// 689.787 us; speedup vs baseline: 1.2111x; 1.2111x over previous
//
#include <hip/hip_runtime.h>
#include <math.h>

// clDice topology loss, round 15: 128x64 output tiles (-17% total work).
// R13/R14 lesson: 5-wave blocks fragment wave slots (2 blocks/CU, 35% occ)
// -> block wave count must divide 4. This round keeps R11's per-lane code
// VERBATIM (12-dw chunks, 3-row erode segs with register carry, 16-out-dw
// dilate halves) and changes only the tiling: output 128 rows x 64 cols,
// region 160 x 96 px -> redundancy 2.25 -> 1.875. Block 512 thr = 8 waves
// (4 erode + 4 dilate, 2/SIMD even). Erode: 54 segs x 4 chunks = 216 lanes,
// active bound [6+it, 153-it] (same algebra as R11's [6+it, 89-it]).
// Dilate: 128 rows x 2 halves = 256 lanes. LDS 161*52*4 = 33.5 KB; VGPR
// ~44-52 -> 4-5 waves/SIMD -> 2 blocks/CU = 16 waves regardless.
// In-place single buffer + 2-barrier phase as R11 (absmax 0.0 R7-R14).

typedef unsigned int u32;
typedef _Float16 h2 __attribute__((ext_vector_type(2)));

#define STRD 52
#define BB   0x7BFF7BFFu   // +65504 x2 (erode pad)
#define NB   0xFBFFFBFFu   // -65504 x2 (dilate edge substitute)

__device__ __forceinline__ u32 ab(u32 hi, u32 lo) {
  return __builtin_amdgcn_alignbit(hi, lo, 16);
}
__device__ __forceinline__ u32 bcu(h2 x) { return __builtin_bit_cast(u32, x); }
__device__ __forceinline__ h2  bch(u32 x) { return __builtin_bit_cast(h2, x); }
__device__ __forceinline__ u32 pmin(u32 a, u32 b) {
  return bcu(__builtin_elementwise_min(bch(a), bch(b)));
}
__device__ __forceinline__ u32 pmax(u32 a, u32 b) {
  return bcu(__builtin_elementwise_max(bch(a), bch(b)));
}
__device__ __forceinline__ u32 pmin3(u32 a, u32 b, u32 c) { return pmin(pmin(a, b), c); }
__device__ __forceinline__ u32 pmax3(u32 a, u32 b, u32 c) { return pmax(pmax(a, b), c); }
// skel >= 0 always, so max(skel, relu(d)) == max(skel, d).
__device__ __forceinline__ u32 skup(u32 sk, u32 im, u32 op) {
  h2 d = bch(im) - bch(op);
  return bcu(__builtin_elementwise_max(bch(sk), d));
}
__device__ __forceinline__ float sigmoidf_(float x) {
  return 1.0f / (1.0f + __expf(-x));
}

__device__ __forceinline__ void load12(const u32* __restrict__ p,
                                       u32* __restrict__ r) {
  uint4 a = *(const uint4*)p;
  uint4 b = *(const uint4*)(p + 4);
  uint4 c = *(const uint4*)(p + 8);
  r[0]=a.x; r[1]=a.y; r[2]=a.z; r[3]=a.w;
  r[4]=b.x; r[5]=b.y; r[6]=b.z; r[7]=b.w;
  r[8]=c.x; r[9]=c.y; r[10]=c.z; r[11]=c.w;
}

__device__ __forceinline__ void store12(u32* __restrict__ q,
                                        const u32* __restrict__ r) {
  *(uint4*)(q)     = make_uint4(r[0], r[1], r[2],  r[3]);
  *(uint4*)(q + 4) = make_uint4(r[4], r[5], r[6],  r[7]);
  *(uint4*)(q + 8) = make_uint4(r[8], r[9], r[10], r[11]);
}

// Horizontal 3-wide min over a 12-dw vmin row; halos pre-fetched.
__device__ __forceinline__ void hrow12(const u32* __restrict__ v,
                                       u32 hl, u32 hr,
                                       u32* __restrict__ o) {
  u32 m0 = ab(v[0], hl);
  #pragma unroll
  for (int i = 0; i < 12; ++i) {
    u32 m1 = (i < 11) ? ab(v[i + 1], v[i]) : ab(hr, v[11]);
    o[i] = pmin3(m0, v[i], m1);
    m0 = m1;
  }
}

// Erode compute (R11 body): reads halo rows as3-1, as3+3 of E^ph from E
// (center rows carried in e0..e2), leaves E^(ph+1) rows as3..as3+2 in
// e0..e2. NO stores (caller stores after the mid-phase barrier).
// FIRST: also load center rows (ph0, no carry yet).
template <bool FIRST>
__device__ __forceinline__ void erode_compute(
    const u32* __restrict__ E,
    int as3, int eoff, int pu, int pd, bool c0, bool c3,
    u32* __restrict__ e0, u32* __restrict__ e1, u32* __restrict__ e2)
{
  const u32* pr = E + (as3 - 1) * STRD + eoff;
  u32 rT[12], rB[12];
  load12(pr, rT);
  if (FIRST) {
    load12(pr + STRD,     e0);
    load12(pr + 2 * STRD, e1);
    load12(pr + 3 * STRD, e2);
  }
  load12(pr + 4 * STRD, rB);
  u32 t[12], v0[12], v1[12], v2[12];
  #pragma unroll
  for (int i = 0; i < 12; ++i) t[i]  = pmin(e0[i], e1[i]);
  #pragma unroll
  for (int i = 0; i < 12; ++i) v0[i] = pmin(rT[i], t[i]);
  #pragma unroll
  for (int i = 0; i < 12; ++i) v1[i] = pmin(t[i], e2[i]);
  #pragma unroll
  for (int i = 0; i < 12; ++i) v2[i] = pmin(e1[i], pmin(e2[i], rB[i]));
  // halos for all 3 rows issued up-front (hide bpermute latency)
  u32 hl0 = (u32)__builtin_amdgcn_ds_bpermute(pu, (int)v0[11]);
  u32 hr0 = (u32)__builtin_amdgcn_ds_bpermute(pd, (int)v0[0]);
  u32 hl1 = (u32)__builtin_amdgcn_ds_bpermute(pu, (int)v1[11]);
  u32 hr1 = (u32)__builtin_amdgcn_ds_bpermute(pd, (int)v1[0]);
  u32 hl2 = (u32)__builtin_amdgcn_ds_bpermute(pu, (int)v2[11]);
  u32 hr2 = (u32)__builtin_amdgcn_ds_bpermute(pd, (int)v2[0]);
  hl0 = c0 ? BB : hl0;  hr0 = c3 ? BB : hr0;
  hl1 = c0 ? BB : hl1;  hr1 = c3 ? BB : hr1;
  hl2 = c0 ? BB : hl2;  hr2 = c3 ? BB : hr2;
  hrow12(v0, hl0, hr0, e0);
  hrow12(v1, hl1, hr1, e1);
  hrow12(v2, hl2, hr2, e2);
}

__device__ __forceinline__ void erode_store(
    u32* __restrict__ E, int as3, int eoff,
    const u32* __restrict__ e0, const u32* __restrict__ e1,
    const u32* __restrict__ e2)
{
  u32* qw = E + as3 * STRD + eoff;
  store12(qw,            e0);
  store12(qw + STRD,     e1);
  store12(qw + 2 * STRD, e2);
}

// Dilate (R11 body): vertical-first 3x3 max over E rows dr-1..dr+1
// (out-of-image rows redirected to -BIG row), horizontal pass, skup
// against img (E^{it-1} center, in regs), img <- reloaded E^{it} center.
__device__ __forceinline__ void dilate_phase(
    const u32* __restrict__ E, const u32* __restrict__ NBR,
    int dr, int db, bool bu, bool bd, bool lfix, bool rfix,
    u32* __restrict__ img, u32* __restrict__ sk)
{
  const u32* pm = bu ? (E + (dr - 1) * STRD + db) : (NBR + db);
  const u32* pc = E + dr * STRD + db;
  const u32* pp = bd ? (E + (dr + 1) * STRD + db) : (NBR + db);
  u32 vm[21];      // indices 3..20 used
  #pragma unroll
  for (int j = 0; j < 6; ++j) {
    uint4 x = *(const uint4*)(pm + 4 * j);
    uint4 y = *(const uint4*)(pc + 4 * j);
    uint4 z = *(const uint4*)(pp + 4 * j);
    u32 xs[4] = {x.x, x.y, x.z, x.w};
    u32 ys[4] = {y.x, y.y, y.z, y.w};
    u32 zs[4] = {z.x, z.y, z.z, z.w};
    #pragma unroll
    for (int k = 0; k < 4; ++k) {
      int i = 4 * j + k;
      if (i >= 3 && i <= 20) vm[i] = pmax3(xs[k], ys[k], zs[k]);
    }
  }
  if (lfix) vm[3]  = (vm[3]  & 0x0000FFFFu) | 0xFBFF0000u;  // col 15 -> -BIG
  if (rfix) vm[20] = (vm[20] & 0xFFFF0000u) | 0x0000FBFFu;  // col 80 -> -BIG
  u32 m0 = ab(vm[4], vm[3]);
  #pragma unroll
  for (int j = 0; j < 4; ++j) {
    const uint4 y = *(const uint4*)(pc + 4 + 4 * j);  // center-row reload
    const u32 yk[4] = {y.x, y.y, y.z, y.w};
    #pragma unroll
    for (int k = 0; k < 4; ++k) {
      const int i = 4 * j + k;
      u32 m1 = ab(vm[i + 5], vm[i + 4]);
      u32 op = pmax3(m0, vm[i + 4], m1);
      m0 = m1;
      sk[i] = skup(sk[i], img[i], op);
      img[i] = yk[k];
    }
  }
}

__global__ __launch_bounds__(512) void skel_tile_kernel(
    const float* __restrict__ pred, const float* __restrict__ gt,
    float* __restrict__ sums)
{
  // In-place buffer: rows 0..159 data (row r at r*STRD), row 160 = -BIG.
  __shared__ __align__(16) u32 L[STRD * 161];
  u32* const E = L;
  const u32* const NBR = L + STRD * 160;

  const int tile = blockIdx.x;   // 16 x-tiles (64 px) x 8 y-tiles (128 px)
  const int b    = blockIdx.y;   // batch 0..31
  const int s    = blockIdx.z;   // 0: skel(sigmoid(pred)), 1: skel(gt)
  const int txI = tile & 15, tyI = tile >> 4;
  const int x0 = txI * 64 - 16, y0 = tyI * 128 - 16;
  const int t  = threadIdx.x;
  const size_t base = (size_t)b << 20;
  const float* __restrict__ src  = s ? gt   : pred;
  const float* __restrict__ osrc = s ? pred : gt;

  // ---- -BIG row init (the only scratch row read) ----
  if (t < STRD) L[STRD * 160 + t] = NB;

  // ---- load rows 5..154 x 12 chunks of 8 halfs; out-of-image = +BIG ----
  for (int i = t; i < 150 * 12; i += 512) {
    int ci = i % 12, row = i / 12 + 5;
    int gy = y0 + row, gx0 = x0 + ci * 8;
    uint4 hv;
    if ((unsigned)gy < 1024u && gx0 >= 0 && gx0 + 8 <= 1024) {
      const size_t g = base + (size_t)gy * 1024 + gx0;
      const float4 f0 = *(const float4*)&src[g];
      const float4 f1 = *(const float4*)&src[g + 4];
      float ff[8] = {f0.x, f0.y, f0.z, f0.w, f1.x, f1.y, f1.z, f1.w};
      u32 d[4];
      #pragma unroll
      for (int e = 0; e < 4; ++e) {
        float a = ff[2 * e], bb2 = ff[2 * e + 1];
        if (s == 0) { a = sigmoidf_(a); bb2 = sigmoidf_(bb2); }
        h2 p; p[0] = (_Float16)a; p[1] = (_Float16)bb2;
        d[e] = bcu(p);
      }
      hv = make_uint4(d[0], d[1], d[2], d[3]);
    } else {
      u32 d[4];
      #pragma unroll
      for (int e = 0; e < 4; ++e) {
        float va = 65504.0f, vb = 65504.0f;
        int gxa = gx0 + 2 * e, gxb = gxa + 1;
        if ((unsigned)gy < 1024u && (unsigned)gxa < 1024u) {
          va = src[base + (size_t)gy * 1024 + gxa];
          if (s == 0) va = sigmoidf_(va);
        }
        if ((unsigned)gy < 1024u && (unsigned)gxb < 1024u) {
          vb = src[base + (size_t)gy * 1024 + gxb];
          if (s == 0) vb = sigmoidf_(vb);
        }
        h2 p; p[0] = (_Float16)va; p[1] = (_Float16)vb;
        d[e] = bcu(p);
      }
      hv = make_uint4(d[0], d[1], d[2], d[3]);
    }
    *(uint4*)&E[row * STRD + ci * 4] = hv;
  }
  __syncthreads();

  const int lane = t & 63, wid = t >> 6;

  // erode role (waves 0-3): seg = t>>2 (0..63; only 0..53 used), ec = t&3
  const int seg = t >> 2, ec = t & 3;
  const int as3 = 3 * seg;
  const bool evalid = (seg <= 53);
  const bool c0 = (ec == 0), c3 = (ec == 3);
  const int pu = ((lane - 1) & 63) * 4;
  const int pd = ((lane + 1) & 63) * 4;
  const int eoff = 12 * ec;

  // dilate role (waves 4-7): d = t-256 (0..255); row dr = 16 + (d>>1),
  // half q = d&1 -> out dw span [db+4, db+19], db = 4 + 16q.
  const int d  = t - 256;
  const int q  = d & 1;
  const int dr = 16 + (d >> 1);
  const int db = 4 + 16 * q;
  const int gyD = y0 + dr;
  const bool bu = (gyD >= 1), bd = (gyD <= 1022);
  const bool lfix = (q == 0) && (txI == 0);
  const bool rfix = (q == 1) && (txI == 15);

  // Role-union register file: erode e0..e2 = st[0..35];
  // dilate img = st[0..15], skel = st[16..31].
  u32 st[36];
  u32* const e0 = st;
  u32* const e1 = st + 12;
  u32* const e2 = st + 24;
  u32* const img = st;
  u32* const sk  = st + 16;

  // ---- phase 0 ----
  const bool a0 = evalid && !(as3 + 2 < 6 || as3 > 153);
  if (wid < 4) {
    if (a0) erode_compute<true>(E, as3, eoff, pu, pd, c0, c3, e0, e1, e2);
  } else {
    #pragma unroll
    for (int i = 0; i < 16; ++i) sk[i] = 0;
    const u32* p = E + dr * STRD + db;
    #pragma unroll
    for (int i = 0; i < 4; ++i) {
      uint4 v = *(const uint4*)(p + 4 + 4 * i);
      img[4*i] = v.x; img[4*i+1] = v.y; img[4*i+2] = v.z; img[4*i+3] = v.w;
    }
  }
  __syncthreads();
  if (wid < 4 && a0) erode_store(E, as3, eoff, e0, e1, e2);
  __syncthreads();

  // ---- phases 1..10 (it==10: dilate-only barrier-free tail) ----
  #pragma unroll 1
  for (int it = 1; it <= 10; ++it) {
    const bool act = (it < 10) && evalid &&
                     !(as3 + 2 < 6 + it || as3 > 153 - it);
    if (wid < 4) {
      if (act) erode_compute<false>(E, as3, eoff, pu, pd, c0, c3, e0, e1, e2);
    } else {
      dilate_phase(E, NBR, dr, db, bu, bd, lfix, rfix, img, sk);
    }
    if (it < 10) {
      __syncthreads();
      if (wid < 4 && act) erode_store(E, as3, eoff, e0, e1, e2);
      __syncthreads();
    }
  }

  // ---- fused reduction: s0 = sum(skel*other), s1 = sum(skel) ----
  float s0 = 0.f, s1 = 0.f;
  if (wid >= 4) {
    const int gxb = x0 + 2 * db + 8;  // global col of first skel half
    const size_t g = base + (size_t)gyD * 1024 + gxb;
    #pragma unroll
    for (int v4i = 0; v4i < 8; ++v4i) {
      const float4 f = *(const float4*)&osrc[g + 4 * v4i];
      float o0 = f.x, o1 = f.y, o2 = f.z, o3 = f.w;
      if (s == 1) {
        o0 = sigmoidf_(o0); o1 = sigmoidf_(o1);
        o2 = sigmoidf_(o2); o3 = sigmoidf_(o3);
      }
      h2 qa = bch(sk[2 * v4i]);
      h2 qb = bch(sk[2 * v4i + 1]);
      float a0 = (float)qa[0], a1 = (float)qa[1];
      float a2 = (float)qb[0], a3 = (float)qb[1];
      s0 += a0 * o0 + a1 * o1 + a2 * o2 + a3 * o3;
      s1 += a0 + a1 + a2 + a3;
    }
  }
  for (int off = 32; off >= 1; off >>= 1) {
    s0 += __shfl_down(s0, off, 64);
    s1 += __shfl_down(s1, off, 64);
  }
  // red area (L row 0, dw 8..15) is disjoint from dilate's reads
  // (rows >= 15); the barrier orders red[] writes before the t==0 read.
  float* red = (float*)L;
  if (lane == 0) { red[wid * 2] = s0; red[wid * 2 + 1] = s1; }
  __syncthreads();
  if (t == 0) {
    atomicAdd(&sums[(s * 32 + b) * 2 + 0],
              red[8] + red[10] + red[12] + red[14]);
    atomicAdd(&sums[(s * 32 + b) * 2 + 1],
              red[9] + red[11] + red[13] + red[15]);
  }
}

__global__ void finalize_kernel(const float* __restrict__ sums,
                                float* __restrict__ out)
{
  const int t = threadIdx.x;  // 64 threads
  float cl = 0.f;
  if (t < 32) {
    float pn = sums[t * 2 + 0],        pd = sums[t * 2 + 1];
    float sn = sums[(32 + t) * 2 + 0], sd = sums[(32 + t) * 2 + 1];
    float tprec = pn / (pd + 1e-6f);
    float tsens = sn / (sd + 1e-6f);
    cl = 2.f * tprec * tsens / (tprec + tsens + 1e-6f);
  }
  for (int off = 32; off >= 1; off >>= 1) cl += __shfl_down(cl, off, 64);
  if (t == 0) out[0] = 1.f - cl / 32.f;
}

extern "C" void kernel_launch(void* const* d_in, const int* in_sizes, int n_in,
                              void* d_out, int out_size, void* d_ws, size_t ws_size,
                              hipStream_t stream) {
  const float* pred = (const float*)d_in[0];
  const float* gt   = (const float*)d_in[1];
  float* sums = (float*)d_ws;  // 128 floats: [tensor][batch][{prod,sum}]
  hipMemsetAsync(sums, 0, 128 * sizeof(float), stream);
  dim3 grid(128, 32, 2);
  skel_tile_kernel<<<grid, dim3(512), 0, stream>>>(pred, gt, sums);
  finalize_kernel<<<1, 64, 0, stream>>>(sums, (float*)d_out);
}

// Round 12
// 637.611 us; speedup vs baseline: 1.3102x; 1.0818x over previous
//
#include <hip/hip_runtime.h>
#include <math.h>

// clDice topology loss, round 16: erode seg->lane permutation for LDS banks.
// R11 champion (491us) + one zero-cost change. Bank model: erode b128 ops
// (STRD=52dw=13 granules) give lane(seg s, chunk c) start granule-group
// g=(7s+d-5) mod 8, d in {0,3,6,1}. Consecutive-seg quarters load groups
// {3,3,2,2,2,2,1,1} -> +50% serialization on 18 erode wave-ops/phase.
// Permuting segs so each quarter-wave holds stride-2 segs
// (quarter q -> segs {2i + 8(q&1) + (q>>1)}) makes the multiset exactly
// 2 per group at quarter/half/full granularity (enumerated). bpermute halo
// exchange is intra-quad (lane+-1, c0/c3 guards) -> unchanged. Stores
// inherit the fix. gfx950's VALUBusy evidently includes LDS execution
// (R5->R6: removing only LDS reads cut busy-time 590->400us), so conflict
// cycles sit inside the binding pipe. Everything else identical to R11.

typedef unsigned int u32;
typedef _Float16 h2 __attribute__((ext_vector_type(2)));

#define STRD 52
#define BB   0x7BFF7BFFu   // +65504 x2 (erode pad)
#define NB   0xFBFFFBFFu   // -65504 x2 (dilate edge substitute)

__device__ __forceinline__ u32 ab(u32 hi, u32 lo) {
  return __builtin_amdgcn_alignbit(hi, lo, 16);
}
__device__ __forceinline__ u32 bcu(h2 x) { return __builtin_bit_cast(u32, x); }
__device__ __forceinline__ h2  bch(u32 x) { return __builtin_bit_cast(h2, x); }
__device__ __forceinline__ u32 pmin(u32 a, u32 b) {
  return bcu(__builtin_elementwise_min(bch(a), bch(b)));
}
__device__ __forceinline__ u32 pmax(u32 a, u32 b) {
  return bcu(__builtin_elementwise_max(bch(a), bch(b)));
}
__device__ __forceinline__ u32 pmin3(u32 a, u32 b, u32 c) { return pmin(pmin(a, b), c); }
__device__ __forceinline__ u32 pmax3(u32 a, u32 b, u32 c) { return pmax(pmax(a, b), c); }
// skel >= 0 always, so max(skel, relu(d)) == max(skel, d).
__device__ __forceinline__ u32 skup(u32 sk, u32 im, u32 op) {
  h2 d = bch(im) - bch(op);
  return bcu(__builtin_elementwise_max(bch(sk), d));
}
__device__ __forceinline__ float sigmoidf_(float x) {
  return 1.0f / (1.0f + __expf(-x));
}

__device__ __forceinline__ void load12(const u32* __restrict__ p,
                                       u32* __restrict__ r) {
  uint4 a = *(const uint4*)p;
  uint4 b = *(const uint4*)(p + 4);
  uint4 c = *(const uint4*)(p + 8);
  r[0]=a.x; r[1]=a.y; r[2]=a.z; r[3]=a.w;
  r[4]=b.x; r[5]=b.y; r[6]=b.z; r[7]=b.w;
  r[8]=c.x; r[9]=c.y; r[10]=c.z; r[11]=c.w;
}

__device__ __forceinline__ void store12(u32* __restrict__ q,
                                        const u32* __restrict__ r) {
  *(uint4*)(q)     = make_uint4(r[0], r[1], r[2],  r[3]);
  *(uint4*)(q + 4) = make_uint4(r[4], r[5], r[6],  r[7]);
  *(uint4*)(q + 8) = make_uint4(r[8], r[9], r[10], r[11]);
}

// Horizontal 3-wide min over a 12-dw vmin row; halos pre-fetched.
__device__ __forceinline__ void hrow12(const u32* __restrict__ v,
                                       u32 hl, u32 hr,
                                       u32* __restrict__ o) {
  u32 m0 = ab(v[0], hl);
  #pragma unroll
  for (int i = 0; i < 12; ++i) {
    u32 m1 = (i < 11) ? ab(v[i + 1], v[i]) : ab(hr, v[11]);
    o[i] = pmin3(m0, v[i], m1);
    m0 = m1;
  }
}

// Erode compute for one lane: reads halo rows as3-1, as3+3 of E^ph from E
// (center rows carried in e0..e2), leaves E^(ph+1) rows as3..as3+2 in
// e0..e2. NO stores (caller stores after the mid-phase barrier).
// FIRST: also load center rows (ph0, no carry yet).
template <bool FIRST>
__device__ __forceinline__ void erode_compute(
    const u32* __restrict__ E,
    int as3, int eoff, int pu, int pd, bool c0, bool c3,
    u32* __restrict__ e0, u32* __restrict__ e1, u32* __restrict__ e2)
{
  const u32* pr = E + (as3 - 1) * STRD + eoff;
  u32 rT[12], rB[12];
  load12(pr, rT);
  if (FIRST) {
    load12(pr + STRD,     e0);
    load12(pr + 2 * STRD, e1);
    load12(pr + 3 * STRD, e2);
  }
  load12(pr + 4 * STRD, rB);
  u32 t[12], v0[12], v1[12], v2[12];
  #pragma unroll
  for (int i = 0; i < 12; ++i) t[i]  = pmin(e0[i], e1[i]);
  #pragma unroll
  for (int i = 0; i < 12; ++i) v0[i] = pmin(rT[i], t[i]);
  #pragma unroll
  for (int i = 0; i < 12; ++i) v1[i] = pmin(t[i], e2[i]);
  #pragma unroll
  for (int i = 0; i < 12; ++i) v2[i] = pmin(e1[i], pmin(e2[i], rB[i]));
  // halos for all 3 rows issued up-front (hide bpermute latency)
  u32 hl0 = (u32)__builtin_amdgcn_ds_bpermute(pu, (int)v0[11]);
  u32 hr0 = (u32)__builtin_amdgcn_ds_bpermute(pd, (int)v0[0]);
  u32 hl1 = (u32)__builtin_amdgcn_ds_bpermute(pu, (int)v1[11]);
  u32 hr1 = (u32)__builtin_amdgcn_ds_bpermute(pd, (int)v1[0]);
  u32 hl2 = (u32)__builtin_amdgcn_ds_bpermute(pu, (int)v2[11]);
  u32 hr2 = (u32)__builtin_amdgcn_ds_bpermute(pd, (int)v2[0]);
  hl0 = c0 ? BB : hl0;  hr0 = c3 ? BB : hr0;
  hl1 = c0 ? BB : hl1;  hr1 = c3 ? BB : hr1;
  hl2 = c0 ? BB : hl2;  hr2 = c3 ? BB : hr2;
  hrow12(v0, hl0, hr0, e0);
  hrow12(v1, hl1, hr1, e1);
  hrow12(v2, hl2, hr2, e2);
}

__device__ __forceinline__ void erode_store(
    u32* __restrict__ E, int as3, int eoff,
    const u32* __restrict__ e0, const u32* __restrict__ e1,
    const u32* __restrict__ e2)
{
  u32* qw = E + as3 * STRD + eoff;
  store12(qw,            e0);
  store12(qw + STRD,     e1);
  store12(qw + 2 * STRD, e2);
}

// One dilate iteration for one lane: vertical-first 3x3 max over E rows
// dr-1..dr+1 (out-of-image rows redirected to the -BIG LDS row), then per
// 4-dw group: horizontal max, skup against img (E^{it-1} center, in regs),
// img <- reloaded E^{it} center. Pure reads.
__device__ __forceinline__ void dilate_phase(
    const u32* __restrict__ E, const u32* __restrict__ NBR,
    int dr, int db, bool bu, bool bd, bool lfix, bool rfix,
    u32* __restrict__ img, u32* __restrict__ sk)
{
  const u32* pm = bu ? (E + (dr - 1) * STRD + db) : (NBR + db);
  const u32* pc = E + dr * STRD + db;
  const u32* pp = bd ? (E + (dr + 1) * STRD + db) : (NBR + db);
  u32 vm[21];      // indices 3..20 used
  #pragma unroll
  for (int j = 0; j < 6; ++j) {
    uint4 x = *(const uint4*)(pm + 4 * j);
    uint4 y = *(const uint4*)(pc + 4 * j);
    uint4 z = *(const uint4*)(pp + 4 * j);
    u32 xs[4] = {x.x, x.y, x.z, x.w};
    u32 ys[4] = {y.x, y.y, y.z, y.w};
    u32 zs[4] = {z.x, z.y, z.z, z.w};
    #pragma unroll
    for (int k = 0; k < 4; ++k) {
      int i = 4 * j + k;
      if (i >= 3 && i <= 20) vm[i] = pmax3(xs[k], ys[k], zs[k]);
    }
  }
  if (lfix) vm[3]  = (vm[3]  & 0x0000FFFFu) | 0xFBFF0000u;  // col 15 -> -BIG
  if (rfix) vm[20] = (vm[20] & 0xFFFF0000u) | 0x0000FBFFu;  // col 80 -> -BIG
  u32 m0 = ab(vm[4], vm[3]);
  #pragma unroll
  for (int j = 0; j < 4; ++j) {
    const uint4 y = *(const uint4*)(pc + 4 + 4 * j);  // center-row reload
    const u32 yk[4] = {y.x, y.y, y.z, y.w};
    #pragma unroll
    for (int k = 0; k < 4; ++k) {
      const int i = 4 * j + k;
      u32 m1 = ab(vm[i + 5], vm[i + 4]);
      u32 op = pmax3(m0, vm[i + 4], m1);
      m0 = m1;
      sk[i] = skup(sk[i], img[i], op);
      img[i] = yk[k];
    }
  }
}

__global__ __launch_bounds__(256, 5) void skel_tile_kernel(
    const float* __restrict__ pred, const float* __restrict__ gt,
    float* __restrict__ sums)
{
  // Single in-place buffer: rows 0..95 data (row r at r*STRD), row 96 = -BIG.
  __shared__ __align__(16) u32 L[STRD * 97];
  u32* const E = L;
  const u32* const NBR = L + STRD * 96;

  const int tile = blockIdx.x;   // 16x16 tiles of 64x64
  const int b    = blockIdx.y;   // batch 0..31
  const int s    = blockIdx.z;   // 0: skel(sigmoid(pred)), 1: skel(gt)
  const int txI = tile & 15, tyI = tile >> 4;
  const int x0 = txI * 64 - 16, y0 = tyI * 64 - 16;
  const int t  = threadIdx.x;
  const size_t base = (size_t)b << 20;
  const float* __restrict__ src  = s ? gt   : pred;
  const float* __restrict__ osrc = s ? pred : gt;

  // ---- -BIG row init (the only scratch row read) ----
  for (int i = t; i < STRD; i += 256) L[STRD * 96 + i] = NB;

  // ---- load rows 5..90 x 12 chunks of 8 halfs; out-of-image = +BIG ----
  for (int i = t; i < 86 * 12; i += 256) {
    int ci = i % 12, row = i / 12 + 5;
    int gy = y0 + row, gx0 = x0 + ci * 8;
    uint4 hv;
    if ((unsigned)gy < 1024u && gx0 >= 0 && gx0 + 8 <= 1024) {
      const size_t g = base + (size_t)gy * 1024 + gx0;
      const float4 f0 = *(const float4*)&src[g];
      const float4 f1 = *(const float4*)&src[g + 4];
      float ff[8] = {f0.x, f0.y, f0.z, f0.w, f1.x, f1.y, f1.z, f1.w};
      u32 d[4];
      #pragma unroll
      for (int e = 0; e < 4; ++e) {
        float a = ff[2 * e], bb2 = ff[2 * e + 1];
        if (s == 0) { a = sigmoidf_(a); bb2 = sigmoidf_(bb2); }
        h2 p; p[0] = (_Float16)a; p[1] = (_Float16)bb2;
        d[e] = bcu(p);
      }
      hv = make_uint4(d[0], d[1], d[2], d[3]);
    } else {
      u32 d[4];
      #pragma unroll
      for (int e = 0; e < 4; ++e) {
        float va = 65504.0f, vb = 65504.0f;
        int gxa = gx0 + 2 * e, gxb = gxa + 1;
        if ((unsigned)gy < 1024u && (unsigned)gxa < 1024u) {
          va = src[base + (size_t)gy * 1024 + gxa];
          if (s == 0) va = sigmoidf_(va);
        }
        if ((unsigned)gy < 1024u && (unsigned)gxb < 1024u) {
          vb = src[base + (size_t)gy * 1024 + gxb];
          if (s == 0) vb = sigmoidf_(vb);
        }
        h2 p; p[0] = (_Float16)va; p[1] = (_Float16)vb;
        d[e] = bcu(p);
      }
      hv = make_uint4(d[0], d[1], d[2], d[3]);
    }
    *(uint4*)&E[row * STRD + ci * 4] = hv;
  }
  __syncthreads();

  const int lane = t & 63, wid = t >> 6;

  // erode role (waves 0-1): seg permuted so each quarter-wave holds
  // stride-2 segs -> uniform LDS bank-group load (see header comment).
  // quad 'inner' = (lane>>2)&3, quarter q = lane>>4:
  //   segL = 2*inner + 8*(q&1) + (q>>1); seg = 16*wid + segL.
  // chunk ec = lane&3 unchanged; bpermute neighbors intra-quad unchanged.
  const int inner = (lane >> 2) & 3, qtr = lane >> 4;
  const int seg = ((t >> 6) << 4) + 2 * inner + 8 * (qtr & 1) + (qtr >> 1);
  const int ec = t & 3;
  const int as3 = 3 * seg;
  const bool c0 = (ec == 0), c3 = (ec == 3);
  const int pu = ((lane - 1) & 63) * 4;
  const int pd = ((lane + 1) & 63) * 4;
  const int eoff = 12 * ec;

  // dilate role (waves 2-3): q = wid-2, row dr = 16+lane
  const int q  = wid - 2;
  const int dr = 16 + lane;
  const int db = 4 + 16 * q;          // first dword of 24-dw read span
  const int gyD = y0 + dr;
  const bool bu = (gyD >= 1), bd = (gyD <= 1022);
  const bool lfix = (q == 0) && (txI == 0);
  const bool rfix = (q == 1) && (txI == 15);

  // Role-union register file: erode e0..e2 = st[0..35];
  // dilate img = st[0..15], skel = st[16..31].
  u32 st[36];
  u32* const e0 = st;
  u32* const e1 = st + 12;
  u32* const e2 = st + 24;
  u32* const img = st;
  u32* const sk  = st + 16;

  // ---- phase 0 ----
  const bool a0 = !(as3 + 2 < 6 || as3 > 89);
  if (wid < 2) {
    if (a0) erode_compute<true>(E, as3, eoff, pu, pd, c0, c3, e0, e1, e2);
  } else {
    #pragma unroll
    for (int i = 0; i < 16; ++i) sk[i] = 0;
    const u32* p = E + dr * STRD + db;
    #pragma unroll
    for (int i = 0; i < 4; ++i) {
      uint4 v = *(const uint4*)(p + 4 + 4 * i);
      img[4*i] = v.x; img[4*i+1] = v.y; img[4*i+2] = v.z; img[4*i+3] = v.w;
    }
  }
  __syncthreads();
  if (wid < 2 && a0) erode_store(E, as3, eoff, e0, e1, e2);
  __syncthreads();

  // ---- phases 1..10 (it==10: dilate only; E^11 never consumed) ----
  #pragma unroll 1
  for (int it = 1; it <= 10; ++it) {
    const bool act = (it < 10) && !(as3 + 2 < 6 + it || as3 > 89 - it);
    if (wid < 2) {
      if (act) erode_compute<false>(E, as3, eoff, pu, pd, c0, c3, e0, e1, e2);
    } else {
      dilate_phase(E, NBR, dr, db, bu, bd, lfix, rfix, img, sk);
    }
    __syncthreads();
    if (wid < 2 && act) erode_store(E, as3, eoff, e0, e1, e2);
    __syncthreads();
  }

  // ---- fused reduction: s0 = sum(skel*other), s1 = sum(skel) ----
  float s0 = 0.f, s1 = 0.f;
  if (wid >= 2) {
    const int gxb = x0 + 2 * db + 8;  // global col of first skel half
    const size_t g = base + (size_t)gyD * 1024 + gxb;
    #pragma unroll
    for (int v4i = 0; v4i < 8; ++v4i) {
      const float4 f = *(const float4*)&osrc[g + 4 * v4i];
      float o0 = f.x, o1 = f.y, o2 = f.z, o3 = f.w;
      if (s == 1) {
        o0 = sigmoidf_(o0); o1 = sigmoidf_(o1);
        o2 = sigmoidf_(o2); o3 = sigmoidf_(o3);
      }
      h2 qa = bch(sk[2 * v4i]);
      h2 qb = bch(sk[2 * v4i + 1]);
      float a0 = (float)qa[0], a1 = (float)qa[1];
      float a2 = (float)qb[0], a3 = (float)qb[1];
      s0 += a0 * o0 + a1 * o1 + a2 * o2 + a3 * o3;
      s1 += a0 + a1 + a2 + a3;
    }
  }
  for (int off = 32; off >= 1; off >>= 1) {
    s0 += __shfl_down(s0, off, 64);
    s1 += __shfl_down(s1, off, 64);
  }
  float* red = (float*)L;
  if (lane == 0) { red[wid * 2] = s0; red[wid * 2 + 1] = s1; }
  __syncthreads();
  if (t == 0) {
    atomicAdd(&sums[(s * 32 + b) * 2 + 0], red[4] + red[6]);
    atomicAdd(&sums[(s * 32 + b) * 2 + 1], red[5] + red[7]);
  }
}

__global__ void finalize_kernel(const float* __restrict__ sums,
                                float* __restrict__ out)
{
  const int t = threadIdx.x;  // 64 threads
  float cl = 0.f;
  if (t < 32) {
    float pn = sums[t * 2 + 0],        pd = sums[t * 2 + 1];
    float sn = sums[(32 + t) * 2 + 0], sd = sums[(32 + t) * 2 + 1];
    float tprec = pn / (pd + 1e-6f);
    float tsens = sn / (sd + 1e-6f);
    cl = 2.f * tprec * tsens / (tprec + tsens + 1e-6f);
  }
  for (int off = 32; off >= 1; off >>= 1) cl += __shfl_down(cl, off, 64);
  if (t == 0) out[0] = 1.f - cl / 32.f;
}

extern "C" void kernel_launch(void* const* d_in, const int* in_sizes, int n_in,
                              void* d_out, int out_size, void* d_ws, size_t ws_size,
                              hipStream_t stream) {
  const float* pred = (const float*)d_in[0];
  const float* gt   = (const float*)d_in[1];
  float* sums = (float*)d_ws;  // 128 floats: [tensor][batch][{prod,sum}]
  hipMemsetAsync(sums, 0, 128 * sizeof(float), stream);
  dim3 grid(256, 32, 2);
  skel_tile_kernel<<<grid, dim3(256), 0, stream>>>(pred, gt, sums);
  finalize_kernel<<<1, 64, 0, stream>>>(sums, (float*)d_out);
}